// Round 3
// baseline (621.817 us; speedup 1.0000x reference)
//
#include <hip/hip_runtime.h>
#include <hip/hip_bf16.h>

#define BTOT 65536
#define DDIM 512
#define CDIM 1000
#define KSEL 45875   // int(65536 * 0.7)

#define L2E 1.44269504088896340736f
#define LN2 0.69314718055994530942f
#define NEG_BIG -1.0e30f

typedef __attribute__((ext_vector_type(8))) short short8;
typedef __attribute__((ext_vector_type(8))) unsigned short ushort8;
typedef __attribute__((ext_vector_type(4))) float f32x4;

__device__ __forceinline__ unsigned short f2bf(float f) {
  unsigned u = __float_as_uint(f);
  u += 0x7FFFu + ((u >> 16) & 1u);
  return (unsigned short)(u >> 16);
}

__device__ __forceinline__ unsigned pk2bf(float lo, float hi) {
  __hip_bfloat162 h = __float22bfloat162_rn(float2{lo, hi});
  return *(unsigned*)&h;   // .x in low 16 bits
}

__device__ __forceinline__ void gload_lds16(const void* g, void* l) {
  __builtin_amdgcn_global_load_lds(
      (const __attribute__((address_space(1))) unsigned int*)g,
      (__attribute__((address_space(3))) unsigned int*)l, 16, 0, 0);
}

// ---- fused prep: B-panel images (swizzled) + hist zero + bias ----
// Panel p (0..7) holds cols [p*128, p*128+128) as [128 cols][512 k] bf16;
// element (cl,k) at byte ((cl<<10)|(k<<1)) ^ ((cl&7)<<4)  within the panel.
__global__ void prep_all(const float* __restrict__ W, const float* __restrict__ b,
                         unsigned short* __restrict__ Wg, float* __restrict__ bp,
                         unsigned* __restrict__ hzero) {
  const int bid = blockIdx.x, tid = threadIdx.x;
  if (bid < 256) {
    const int idx = bid * 256 + tid;      // 65536
    const int c  = idx & 1023;            // padded col
    const int k8 = idx >> 10;             // 0..63
    const int p = c >> 7, cl = c & 127;
    ushort8 v;
#pragma unroll
    for (int j = 0; j < 8; ++j) {
      const int k = k8 * 8 + j;
      v[j] = (c < CDIM) ? f2bf(W[k * CDIM + c]) : (unsigned short)0;
    }
    const unsigned off = ((((unsigned)cl) << 10) | (((unsigned)k8) << 4)) ^
                         ((((unsigned)cl) & 7u) << 4);
    *(ushort8*)((char*)Wg + (size_t)p * 131072 + off) = v;
  } else if (bid < 384) {
    ((uint4*)hzero)[(bid - 256) * 256 + tid] = (uint4){0, 0, 0, 0};  // 512 KiB (hHi+hLo)
  } else {
    for (int i = tid; i < 1024; i += 256) bp[i] = (i < CDIM) ? b[i] * L2E : NEG_BIG;
  }
}

// ---- persistent fused GEMM + partial fixed-max LSE ----
// 256 blocks (1/CU) x 512 thr (8 waves). Block = (xcd-stripe, panel).
// B-panel staged ONCE into 128KB LDS; main loop barrier-free.
__launch_bounds__(512, 2)
__global__ void ohem_losses(const float* __restrict__ feat,
                            const int* __restrict__ targets,
                            const unsigned short* __restrict__ Wg,
                            const float* __restrict__ bpad,
                            float* __restrict__ spart,
                            float* __restrict__ tvpart) {
  extern __shared__ char lbuf[];          // 131072 B
  const int tid = threadIdx.x, lane = tid & 63, w = tid >> 6;
  const int l15 = lane & 15, lgrp = lane >> 4;
  const int bid = blockIdx.x;
  const int xcd = bid & 7, q = bid >> 3;
  const int p = q & 7, stp8 = q >> 3;     // panel, stripe-slot
  const int gs = xcd * 4 + stp8;          // stripe 0..31 (8 panel-blocks share one XCD)
  const int rowS = gs << 11;              // *2048

  // stage panel p once: 131072 B = 16 iters x 512 thr x 16B (linear dest = swizzled image)
  const char* src = (const char*)Wg + (size_t)p * 131072;
#pragma unroll
  for (int r = 0; r < 16; ++r) {
    const int off = (r * 512 + tid) * 16;
    gload_lds16(src + off, lbuf + off);
  }

  const int p128 = p << 7;
  float bb[8]; int colc[8];
#pragma unroll
  for (int cf = 0; cf < 8; ++cf) {
    colc[cf] = p128 + cf * 16 + l15;
    bb[cf] = bpad[colc[cf]];
  }

  __syncthreads();   // panel resident (drains vmcnt); the ONLY barrier

  const unsigned xm   = ((unsigned)(l15 & 7)) << 4;
  const unsigned bofs = (((unsigned)l15) << 10) | (((unsigned)lgrp) << 4);

  for (int it = 0; it < 8; ++it) {
    const int rowB = rowS + (it << 8) + (w << 5);   // 32 rows for this wave
    const float* a0 = feat + (size_t)(rowB + l15) * DDIM + lgrp * 8;

    f32x4 acc[2][8];
#pragma unroll
    for (int g = 0; g < 2; ++g)
#pragma unroll
      for (int cf = 0; cf < 8; ++cf) acc[g][cf] = (f32x4){0.f, 0.f, 0.f, 0.f};

#pragma unroll
    for (int ks = 0; ks < 16; ++ks) {
      short8 ag[2];
#pragma unroll
      for (int g = 0; g < 2; ++g) {
        const float* ap = a0 + g * (16 * DDIM) + ks * 32;
        const float4 f0 = *(const float4*)ap;
        const float4 f1 = *(const float4*)(ap + 4);
        union { unsigned u[4]; short8 s; } cv;
        cv.u[0] = pk2bf(f0.x, f0.y);
        cv.u[1] = pk2bf(f0.z, f0.w);
        cv.u[2] = pk2bf(f1.x, f1.y);
        cv.u[3] = pk2bf(f1.z, f1.w);
        ag[g] = cv.s;
      }
      const unsigned kb = (bofs + ((unsigned)ks << 6)) ^ xm;   // xor AFTER full low-addr assembly
#pragma unroll
      for (int cf = 0; cf < 8; ++cf) {
        const short8 bfr = *(const short8*)(lbuf + kb + (unsigned)cf * 16384u);
        acc[0][cf] = __builtin_amdgcn_mfma_f32_16x16x32_bf16(ag[0], bfr, acc[0][cf], 0, 0, 0);
        acc[1][cf] = __builtin_amdgcn_mfma_f32_16x16x32_bf16(ag[1], bfr, acc[1][cf], 0, 0, 0);
      }
    }

    // partial LSE epilogue: C layout col = l15, row = lgrp*4 + reg
#pragma unroll
    for (int g = 0; g < 2; ++g)
#pragma unroll
      for (int r = 0; r < 4; ++r) {
        const int row = rowB + g * 16 + lgrp * 4 + r;
        const int tc = targets[row];
        float s = 0.f, tv = NEG_BIG;
#pragma unroll
        for (int cf = 0; cf < 8; ++cf) {
          const float z = fmaf(acc[g][cf][r], L2E, bb[cf]);
          if (colc[cf] == tc) tv = z;
          s += __builtin_amdgcn_exp2f(z);
        }
#pragma unroll
        for (int st = 1; st <= 8; st <<= 1) {
          s += __shfl_xor(s, st, 64);
          tv = fmaxf(tv, __shfl_xor(tv, st, 64));
        }
        if (l15 == 0) {
          spart[(size_t)p * BTOT + row]  = s;
          tvpart[(size_t)p * BTOT + row] = tv;
        }
      }
  }
}

// ---- combine 8 panel-partials -> loss, + hi-16 histogram ----
__global__ void combine_hist(const float* __restrict__ spart,
                             const float* __restrict__ tvpart,
                             float* __restrict__ losses,
                             unsigned* __restrict__ hHi) {
  const int row = blockIdx.x * 256 + threadIdx.x;
  float s = 0.f, tv = NEG_BIG;
#pragma unroll
  for (int p = 0; p < 8; ++p) {
    s  += spart[(size_t)p * BTOT + row];
    tv  = fmaxf(tv, tvpart[(size_t)p * BTOT + row]);
  }
  float loss = LN2 * (__builtin_amdgcn_logf(s) - tv);
  loss = fmaxf(loss, 0.f);
  losses[row] = loss;
  atomicAdd(&hHi[__float_as_uint(loss) >> 16], 1u);
}

// ---- level scan: find bin containing the k-th largest; 1 block x 256 threads ----
__global__ void scan_level(const unsigned* __restrict__ hist,
                           unsigned* __restrict__ state, const int level) {
  const int t = threadIdx.x;
  __shared__ unsigned sh[256];
  const unsigned k       = (level == 0) ? (unsigned)KSEL : state[1];
  const unsigned oldpref = (level == 0) ? 0u : state[0];

  unsigned gs = 0;
  const uint4* hp = (const uint4*)(hist + t * 256);
#pragma unroll 4
  for (int i = 0; i < 64; ++i) { const uint4 h = hp[i]; gs += h.x + h.y + h.z + h.w; }
  sh[t] = gs;
  __syncthreads();
  for (int off = 1; off < 256; off <<= 1) {   // inclusive suffix scan
    unsigned v = sh[t];
    if (t + off < 256) v += sh[t + off];
    __syncthreads();
    sh[t] = v;
    __syncthreads();
  }
  const unsigned incl  = sh[t];
  const unsigned above = (t < 255) ? sh[t + 1] : 0u;
  if (above < k && k <= incl) {          // exactly one thread
    unsigned kk = k - above;
    int bkt = 255;
    for (; bkt > 0; --bkt) {
      const unsigned c = hist[t * 256 + bkt];
      if (kk <= c) break;
      kk -= c;
    }
    const unsigned bin = (unsigned)(t * 256 + bkt);
    if (level == 0) { state[0] = bin << 16;      state[1] = kk; }
    else            { state[0] = oldpref | bin;  state[1] = kk; }
  }
}

__global__ void hist_lo(const float* __restrict__ losses,
                        const unsigned* __restrict__ state,
                        unsigned* __restrict__ hLo) {
  const unsigned pref = state[0] >> 16;
  const int i = blockIdx.x * 256 + threadIdx.x;
  const unsigned u = ((const unsigned*)losses)[i];
  if ((u >> 16) == pref) atomicAdd(&hLo[u & 0xFFFFu], 1u);
}

// ---- deterministic sum/count of values strictly greater than threshold ----
__global__ void ohem_sum(const float* __restrict__ losses,
                         const unsigned* __restrict__ state,
                         float* __restrict__ psum, unsigned* __restrict__ pcnt) {
  const unsigned ut = state[0];
  const int i = blockIdx.x * 256 + threadIdx.x;
  const float v = losses[i];
  const unsigned u = __float_as_uint(v);
  float    sv = (u > ut) ? v  : 0.f;
  unsigned sc = (u > ut) ? 1u : 0u;
#pragma unroll
  for (int st = 32; st >= 1; st >>= 1) {
    sv += __shfl_xor(sv, st, 64);
    sc += __shfl_xor(sc, st, 64);
  }
  __shared__ float    wsum[4];
  __shared__ unsigned wcnt[4];
  const int w = threadIdx.x >> 6;
  if ((threadIdx.x & 63) == 0) { wsum[w] = sv; wcnt[w] = sc; }
  __syncthreads();
  if (threadIdx.x == 0) {
    psum[blockIdx.x] = wsum[0] + wsum[1] + wsum[2] + wsum[3];
    pcnt[blockIdx.x] = wcnt[0] + wcnt[1] + wcnt[2] + wcnt[3];
  }
}

__global__ void ohem_final(const float* __restrict__ psum,
                           const unsigned* __restrict__ pcnt,
                           const unsigned* __restrict__ state,
                           float* __restrict__ out) {
  float    sv = psum[threadIdx.x];
  unsigned sc = pcnt[threadIdx.x];
#pragma unroll
  for (int st = 32; st >= 1; st >>= 1) {
    sv += __shfl_xor(sv, st, 64);
    sc += __shfl_xor(sc, st, 64);
  }
  __shared__ float    wsum[4];
  __shared__ unsigned wcnt[4];
  const int w = threadIdx.x >> 6;
  if ((threadIdx.x & 63) == 0) { wsum[w] = sv; wcnt[w] = sc; }
  __syncthreads();
  if (threadIdx.x == 0) {
    const float    sum = wsum[0] + wsum[1] + wsum[2] + wsum[3];
    const unsigned cnt = wcnt[0] + wcnt[1] + wcnt[2] + wcnt[3];
    const float t = __uint_as_float(state[0]);
    out[0] = (sum + (float)(KSEL - cnt) * t) / (float)KSEL;
  }
}

extern "C" void kernel_launch(void* const* d_in, const int* in_sizes, int n_in,
                              void* d_out, int out_size, void* d_ws, size_t ws_size,
                              hipStream_t stream) {
  const float* feat    = (const float*)d_in[0];
  const int*   targets = (const int*)d_in[1];
  const float* W       = (const float*)d_in[2];
  const float* b       = (const float*)d_in[3];
  float* out = (float*)d_out;

  char* ws = (char*)d_ws;
  unsigned short* Wg     = (unsigned short*)ws;              // 1 MiB (8 swizzled panels)
  float*          bp     = (float*)(ws + 1048576);           // 4 KiB
  float*          spart  = (float*)(ws + 1052672);           // 2 MiB
  float*          tvpart = (float*)(ws + 3149824);           // 2 MiB
  float*          losses = (float*)(ws + 5246976);           // 256 KiB
  unsigned*       hHi    = (unsigned*)(ws + 5509120);        // 256 KiB
  unsigned*       hLo    = (unsigned*)(ws + 5771264);        // 256 KiB (contiguous after hHi)
  unsigned*       state  = (unsigned*)(ws + 6033408);        // 256 B
  float*          psum   = (float*)(ws + 6033664);           // 1 KiB
  unsigned*       pcnt   = (unsigned*)(ws + 6034688);        // 1 KiB

  hipFuncSetAttribute((const void*)ohem_losses,
                      hipFuncAttributeMaxDynamicSharedMemorySize, 131072);

  prep_all<<<385, 256, 0, stream>>>(W, b, Wg, bp, hHi);      // hHi..hLo zeroed
  ohem_losses<<<256, 512, 131072, stream>>>(feat, targets, Wg, bp, spart, tvpart);
  combine_hist<<<256, 256, 0, stream>>>(spart, tvpart, losses, hHi);
  scan_level<<<1, 256, 0, stream>>>(hHi, state, 0);
  hist_lo<<<256, 256, 0, stream>>>(losses, state, hLo);
  scan_level<<<1, 256, 0, stream>>>(hLo, state, 1);
  ohem_sum<<<256, 256, 0, stream>>>(losses, state, psum, pcnt);
  ohem_final<<<1, 256, 0, stream>>>(psum, pcnt, state, out);
}

// Round 4
// 535.193 us; speedup vs baseline: 1.1619x; 1.1619x over previous
//
#include <hip/hip_runtime.h>
#include <hip/hip_bf16.h>

#define BTOT 65536
#define DDIM 512
#define CDIM 1000
#define KSEL 45875   // int(65536 * 0.7)

#define L2E 1.44269504088896340736f
#define LN2 0.69314718055994530942f
#define NEG_BIG -1.0e30f

typedef __attribute__((ext_vector_type(8))) short short8;
typedef __attribute__((ext_vector_type(8))) unsigned short ushort8;
typedef __attribute__((ext_vector_type(4))) float f32x4;

__device__ __forceinline__ unsigned short f2bf(float f) {
  unsigned u = __float_as_uint(f);
  u += 0x7FFFu + ((u >> 16) & 1u);
  return (unsigned short)(u >> 16);
}

__device__ __forceinline__ void gload_lds16(const void* g, void* l) {
  __builtin_amdgcn_global_load_lds(
      (const __attribute__((address_space(1))) unsigned int*)g,
      (__attribute__((address_space(3))) unsigned int*)l, 16, 0, 0);
}

// ---- fused prep: B-panel images (swizzled) + hist zero + bias ----
// Panel p (0..7) holds cols [p*128, p*128+128) as [128 cols][512 k] bf16;
// element (cl,k) at byte ((cl<<10)|(k<<1)) ^ ((cl&7)<<4)  within the panel.
__global__ void prep_all(const float* __restrict__ W, const float* __restrict__ b,
                         unsigned short* __restrict__ Wg, float* __restrict__ bp,
                         unsigned* __restrict__ hzero) {
  const int bid = blockIdx.x, tid = threadIdx.x;
  if (bid < 256) {
    const int idx = bid * 256 + tid;      // 65536
    const int c  = idx & 1023;            // padded col
    const int k8 = idx >> 10;             // 0..63
    const int p = c >> 7, cl = c & 127;
    ushort8 v;
#pragma unroll
    for (int j = 0; j < 8; ++j) {
      const int k = k8 * 8 + j;
      v[j] = (c < CDIM) ? f2bf(W[k * CDIM + c]) : (unsigned short)0;
    }
    const unsigned off = ((((unsigned)cl) << 10) | (((unsigned)k8) << 4)) ^
                         ((((unsigned)cl) & 7u) << 4);
    *(ushort8*)((char*)Wg + (size_t)p * 131072 + off) = v;
  } else if (bid < 384) {
    ((uint4*)hzero)[(bid - 256) * 256 + tid] = (uint4){0, 0, 0, 0};  // 512 KiB (hHi+hLo)
  } else {
    for (int i = tid; i < 1024; i += 256) bp[i] = (i < CDIM) ? b[i] * L2E : NEG_BIG;
  }
}

// ---- persistent fused GEMM + partial fixed-max LSE ----
// 256 blocks (1/CU) x 512 thr (8 waves). Block = (xcd-stripe, panel).
// B-panel staged ONCE into 128KB LDS; main loop barrier-free; 64 rows/wave/iter.
__launch_bounds__(512, 2)
__global__ void ohem_losses(const float* __restrict__ feat,
                            const int* __restrict__ targets,
                            const unsigned short* __restrict__ Wg,
                            const float* __restrict__ bpad,
                            float* __restrict__ spart,
                            float* __restrict__ tvpart) {
  extern __shared__ char lbuf[];          // 131072 B
  const int tid = threadIdx.x, lane = tid & 63, w = tid >> 6;
  const int l15 = lane & 15, lgrp = lane >> 4;
  const int bid = blockIdx.x;
  const int xcd = bid & 7, q = bid >> 3;
  const int p = q & 7, stp8 = q >> 3;     // panel, stripe-slot
  const int gs = xcd * 4 + stp8;          // stripe 0..31 (8 panel-blocks share one XCD)
  const int rowS = gs << 11;              // *2048

  // stage panel p once: 131072 B = 16 iters x 512 thr x 16B (linear dest = swizzled image)
  const char* src = (const char*)Wg + (size_t)p * 131072;
#pragma unroll
  for (int r = 0; r < 16; ++r) {
    const int off = (r * 512 + tid) * 16;
    gload_lds16(src + off, lbuf + off);
  }

  const int p128 = p << 7;
  float bb[8]; int colc[8];
#pragma unroll
  for (int cf = 0; cf < 8; ++cf) {
    colc[cf] = p128 + cf * 16 + l15;
    bb[cf] = bpad[colc[cf]];
  }

  __syncthreads();   // panel resident (drains vmcnt); the ONLY barrier

  const unsigned xm   = ((unsigned)(l15 & 7)) << 4;
  const unsigned bofs = (((unsigned)l15) << 10) | (((unsigned)lgrp) << 4);

  for (int it = 0; it < 4; ++it) {
    const int rowB = rowS + (it << 9) + (w << 6);   // 64 rows for this wave
    const float* a0 = feat + (size_t)(rowB + l15) * DDIM + lgrp * 8;

    f32x4 acc[4][8];
#pragma unroll
    for (int rf = 0; rf < 4; ++rf)
#pragma unroll
      for (int cf = 0; cf < 8; ++cf) acc[rf][cf] = (f32x4){0.f, 0.f, 0.f, 0.f};

#pragma unroll
    for (int ks = 0; ks < 16; ++ks) {
      short8 ag[4];
#pragma unroll
      for (int rf = 0; rf < 4; ++rf) {
        const float* ap = a0 + rf * (16 * DDIM) + ks * 32;
        const float4 f0 = *(const float4*)ap;
        const float4 f1 = *(const float4*)(ap + 4);
        short8 v;
        v[0] = (short)f2bf(f0.x); v[1] = (short)f2bf(f0.y);
        v[2] = (short)f2bf(f0.z); v[3] = (short)f2bf(f0.w);
        v[4] = (short)f2bf(f1.x); v[5] = (short)f2bf(f1.y);
        v[6] = (short)f2bf(f1.z); v[7] = (short)f2bf(f1.w);
        ag[rf] = v;
      }
      const unsigned kb = (bofs | ((unsigned)ks << 6)) ^ xm;
#pragma unroll
      for (int cf = 0; cf < 8; ++cf) {
        const short8 bfr = *(const short8*)(lbuf + kb + (unsigned)cf * 16384u);
        acc[0][cf] = __builtin_amdgcn_mfma_f32_16x16x32_bf16(ag[0], bfr, acc[0][cf], 0, 0, 0);
        acc[1][cf] = __builtin_amdgcn_mfma_f32_16x16x32_bf16(ag[1], bfr, acc[1][cf], 0, 0, 0);
        acc[2][cf] = __builtin_amdgcn_mfma_f32_16x16x32_bf16(ag[2], bfr, acc[2][cf], 0, 0, 0);
        acc[3][cf] = __builtin_amdgcn_mfma_f32_16x16x32_bf16(ag[3], bfr, acc[3][cf], 0, 0, 0);
      }
    }

    // partial LSE epilogue: C layout col = l15, row = lgrp*4 + reg
#pragma unroll
    for (int rf = 0; rf < 4; ++rf)
#pragma unroll
      for (int r = 0; r < 4; ++r) {
        const int row = rowB + rf * 16 + lgrp * 4 + r;
        const int tc = targets[row];
        float s = 0.f, tv = NEG_BIG;
#pragma unroll
        for (int cf = 0; cf < 8; ++cf) {
          const float z = fmaf(acc[rf][cf][r], L2E, bb[cf]);
          if (colc[cf] == tc) tv = z;
          s += __builtin_amdgcn_exp2f(z);
        }
#pragma unroll
        for (int st = 1; st <= 8; st <<= 1) {
          s += __shfl_xor(s, st, 64);
          tv = fmaxf(tv, __shfl_xor(tv, st, 64));
        }
        if (l15 == 0) {
          spart[(size_t)p * BTOT + row]  = s;
          tvpart[(size_t)p * BTOT + row] = tv;
        }
      }
  }
}

// ---- combine 8 panel-partials -> loss, + hi-16 histogram ----
__global__ void combine_hist(const float* __restrict__ spart,
                             const float* __restrict__ tvpart,
                             float* __restrict__ losses,
                             unsigned* __restrict__ hHi) {
  const int row = blockIdx.x * 256 + threadIdx.x;
  float s = 0.f, tv = NEG_BIG;
#pragma unroll
  for (int p = 0; p < 8; ++p) {
    s  += spart[(size_t)p * BTOT + row];
    tv  = fmaxf(tv, tvpart[(size_t)p * BTOT + row]);
  }
  float loss = LN2 * (__builtin_amdgcn_logf(s) - tv);
  loss = fmaxf(loss, 0.f);
  losses[row] = loss;
  atomicAdd(&hHi[__float_as_uint(loss) >> 16], 1u);
}

// ---- level scan: find bin containing the k-th largest; 1 block x 256 threads ----
__global__ void scan_level(const unsigned* __restrict__ hist,
                           unsigned* __restrict__ state, const int level) {
  const int t = threadIdx.x;
  __shared__ unsigned sh[256];
  const unsigned k       = (level == 0) ? (unsigned)KSEL : state[1];
  const unsigned oldpref = (level == 0) ? 0u : state[0];

  unsigned gs = 0;
  const uint4* hp = (const uint4*)(hist + t * 256);
#pragma unroll 4
  for (int i = 0; i < 64; ++i) { const uint4 h = hp[i]; gs += h.x + h.y + h.z + h.w; }
  sh[t] = gs;
  __syncthreads();
  for (int off = 1; off < 256; off <<= 1) {   // inclusive suffix scan
    unsigned v = sh[t];
    if (t + off < 256) v += sh[t + off];
    __syncthreads();
    sh[t] = v;
    __syncthreads();
  }
  const unsigned incl  = sh[t];
  const unsigned above = (t < 255) ? sh[t + 1] : 0u;
  if (above < k && k <= incl) {          // exactly one thread
    unsigned kk = k - above;
    int bkt = 255;
    for (; bkt > 0; --bkt) {
      const unsigned c = hist[t * 256 + bkt];
      if (kk <= c) break;
      kk -= c;
    }
    const unsigned bin = (unsigned)(t * 256 + bkt);
    if (level == 0) { state[0] = bin << 16;      state[1] = kk; }
    else            { state[0] = oldpref | bin;  state[1] = kk; }
  }
}

__global__ void hist_lo(const float* __restrict__ losses,
                        const unsigned* __restrict__ state,
                        unsigned* __restrict__ hLo) {
  const unsigned pref = state[0] >> 16;
  const int i = blockIdx.x * 256 + threadIdx.x;
  const unsigned u = ((const unsigned*)losses)[i];
  if ((u >> 16) == pref) atomicAdd(&hLo[u & 0xFFFFu], 1u);
}

// ---- deterministic sum/count of values strictly greater than threshold ----
__global__ void ohem_sum(const float* __restrict__ losses,
                         const unsigned* __restrict__ state,
                         float* __restrict__ psum, unsigned* __restrict__ pcnt) {
  const unsigned ut = state[0];
  const int i = blockIdx.x * 256 + threadIdx.x;
  const float v = losses[i];
  const unsigned u = __float_as_uint(v);
  float    sv = (u > ut) ? v  : 0.f;
  unsigned sc = (u > ut) ? 1u : 0u;
#pragma unroll
  for (int st = 32; st >= 1; st >>= 1) {
    sv += __shfl_xor(sv, st, 64);
    sc += __shfl_xor(sc, st, 64);
  }
  __shared__ float    wsum[4];
  __shared__ unsigned wcnt[4];
  const int w = threadIdx.x >> 6;
  if ((threadIdx.x & 63) == 0) { wsum[w] = sv; wcnt[w] = sc; }
  __syncthreads();
  if (threadIdx.x == 0) {
    psum[blockIdx.x] = wsum[0] + wsum[1] + wsum[2] + wsum[3];
    pcnt[blockIdx.x] = wcnt[0] + wcnt[1] + wcnt[2] + wcnt[3];
  }
}

__global__ void ohem_final(const float* __restrict__ psum,
                           const unsigned* __restrict__ pcnt,
                           const unsigned* __restrict__ state,
                           float* __restrict__ out) {
  float    sv = psum[threadIdx.x];
  unsigned sc = pcnt[threadIdx.x];
#pragma unroll
  for (int st = 32; st >= 1; st >>= 1) {
    sv += __shfl_xor(sv, st, 64);
    sc += __shfl_xor(sc, st, 64);
  }
  __shared__ float    wsum[4];
  __shared__ unsigned wcnt[4];
  const int w = threadIdx.x >> 6;
  if ((threadIdx.x & 63) == 0) { wsum[w] = sv; wcnt[w] = sc; }
  __syncthreads();
  if (threadIdx.x == 0) {
    const float    sum = wsum[0] + wsum[1] + wsum[2] + wsum[3];
    const unsigned cnt = wcnt[0] + wcnt[1] + wcnt[2] + wcnt[3];
    const float t = __uint_as_float(state[0]);
    out[0] = (sum + (float)(KSEL - cnt) * t) / (float)KSEL;
  }
}

extern "C" void kernel_launch(void* const* d_in, const int* in_sizes, int n_in,
                              void* d_out, int out_size, void* d_ws, size_t ws_size,
                              hipStream_t stream) {
  const float* feat    = (const float*)d_in[0];
  const int*   targets = (const int*)d_in[1];
  const float* W       = (const float*)d_in[2];
  const float* b       = (const float*)d_in[3];
  float* out = (float*)d_out;

  char* ws = (char*)d_ws;
  unsigned short* Wg     = (unsigned short*)ws;              // 1 MiB (8 swizzled panels)
  float*          bp     = (float*)(ws + 1048576);           // 4 KiB
  float*          spart  = (float*)(ws + 1052672);           // 2 MiB
  float*          tvpart = (float*)(ws + 3149824);           // 2 MiB
  float*          losses = (float*)(ws + 5246976);           // 256 KiB
  unsigned*       hHi    = (unsigned*)(ws + 5509120);        // 256 KiB
  unsigned*       hLo    = (unsigned*)(ws + 5771264);        // 256 KiB (contiguous after hHi)
  unsigned*       state  = (unsigned*)(ws + 6033408);        // 256 B
  float*          psum   = (float*)(ws + 6033664);           // 1 KiB
  unsigned*       pcnt   = (unsigned*)(ws + 6034688);        // 1 KiB

  hipFuncSetAttribute((const void*)ohem_losses,
                      hipFuncAttributeMaxDynamicSharedMemorySize, 131072);

  prep_all<<<385, 256, 0, stream>>>(W, b, Wg, bp, hHi);      // hHi..hLo zeroed
  ohem_losses<<<256, 512, 131072, stream>>>(feat, targets, Wg, bp, spart, tvpart);
  combine_hist<<<256, 256, 0, stream>>>(spart, tvpart, losses, hHi);
  scan_level<<<1, 256, 0, stream>>>(hHi, state, 0);
  hist_lo<<<256, 256, 0, stream>>>(losses, state, hLo);
  scan_level<<<1, 256, 0, stream>>>(hLo, state, 1);
  ohem_sum<<<256, 256, 0, stream>>>(losses, state, psum, pcnt);
  ohem_final<<<1, 256, 0, stream>>>(psum, pcnt, state, out);
}

// Round 5
// 534.828 us; speedup vs baseline: 1.1626x; 1.0007x over previous
//
#include <hip/hip_runtime.h>
#include <hip/hip_bf16.h>

#define BTOT 65536
#define DDIM 512
#define CDIM 1000
#define KSEL 45875   // int(65536 * 0.7)

#define L2E 1.44269504088896340736f
#define LN2 0.69314718055994530942f
#define NEG_BIG -1.0e30f

typedef __attribute__((ext_vector_type(8))) short short8;
typedef __attribute__((ext_vector_type(8))) unsigned short ushort8;
typedef __attribute__((ext_vector_type(4))) float f32x4;

__device__ __forceinline__ unsigned short f2bf(float f) {
  unsigned u = __float_as_uint(f);
  u += 0x7FFFu + ((u >> 16) & 1u);
  return (unsigned short)(u >> 16);
}

__device__ __forceinline__ void gload_lds16(const void* g, void* l) {
  __builtin_amdgcn_global_load_lds(
      (const __attribute__((address_space(1))) unsigned int*)g,
      (__attribute__((address_space(3))) unsigned int*)l, 16, 0, 0);
}

// ---- fused prep: B-panel images (swizzled) + hist zero + bias ----
// Panel p (0..7) holds cols [p*128, p*128+128) as [128 cols][512 k] bf16;
// element (cl,k) at byte ((cl<<10)|(k<<1)) ^ ((cl&7)<<4)  within the panel.
__global__ void prep_all(const float* __restrict__ W, const float* __restrict__ b,
                         unsigned short* __restrict__ Wg, float* __restrict__ bp,
                         unsigned* __restrict__ hzero) {
  const int bid = blockIdx.x, tid = threadIdx.x;
  if (bid < 256) {
    const int idx = bid * 256 + tid;      // 65536
    const int c  = idx & 1023;            // padded col
    const int k8 = idx >> 10;             // 0..63
    const int p = c >> 7, cl = c & 127;
    ushort8 v;
#pragma unroll
    for (int j = 0; j < 8; ++j) {
      const int k = k8 * 8 + j;
      v[j] = (c < CDIM) ? f2bf(W[k * CDIM + c]) : (unsigned short)0;
    }
    const unsigned off = ((((unsigned)cl) << 10) | (((unsigned)k8) << 4)) ^
                         ((((unsigned)cl) & 7u) << 4);
    *(ushort8*)((char*)Wg + (size_t)p * 131072 + off) = v;
  } else if (bid < 384) {
    ((uint4*)hzero)[(bid - 256) * 256 + tid] = (uint4){0, 0, 0, 0};  // 512 KiB (hHi+hLo)
  } else {
    for (int i = tid; i < 1024; i += 256) bp[i] = (i < CDIM) ? b[i] * L2E : NEG_BIG;
  }
}

// ---- persistent fused GEMM + partial fixed-max LSE ----
// 256 blocks (1/CU, LDS-capped) x 512 thr (8 waves). Block = (xcd-stripe, panel).
// B-panel staged ONCE into 128KB LDS; main loop barrier-free; 64 rows/wave/iter.
// NOTE: 2nd launch_bounds arg behaves as blocks/CU here (VGPR_Count=128 across
// R1-R4 proves a 16-wave budget); (512,1) -> 8 waves/CU -> 256-VGPR cap.
__launch_bounds__(512, 1)
__global__ void ohem_losses(const float* __restrict__ feat,
                            const int* __restrict__ targets,
                            const unsigned short* __restrict__ Wg,
                            const float* __restrict__ bpad,
                            float* __restrict__ spart,
                            float* __restrict__ tvpart) {
  extern __shared__ char lbuf[];          // 131072 B
  const int tid = threadIdx.x, lane = tid & 63, w = tid >> 6;
  const int l15 = lane & 15, lgrp = lane >> 4;
  const int bid = blockIdx.x;
  const int xcd = bid & 7, q = bid >> 3;
  const int p = q & 7, stp8 = q >> 3;     // panel, stripe-slot
  const int gs = xcd * 4 + stp8;          // stripe 0..31 (8 panel-blocks share one XCD)
  const int rowS = gs << 11;              // *2048

  // stage panel p once: 131072 B = 16 iters x 512 thr x 16B (linear dest = swizzled image)
  const char* src = (const char*)Wg + (size_t)p * 131072;
#pragma unroll
  for (int r = 0; r < 16; ++r) {
    const int off = (r * 512 + tid) * 16;
    gload_lds16(src + off, lbuf + off);
  }

  __syncthreads();   // panel resident (drains vmcnt); the ONLY barrier

  const int p128 = p << 7;
  const unsigned xm   = ((unsigned)(l15 & 7)) << 4;
  const unsigned bofs = (((unsigned)l15) << 10) | (((unsigned)lgrp) << 4);

  for (int it = 0; it < 4; ++it) {
    const int rowB = rowS + (it << 9) + (w << 6);   // 64 rows for this wave
    const float* a0 = feat + (size_t)(rowB + l15) * DDIM + lgrp * 8;

    f32x4 acc[4][8];
#pragma unroll
    for (int rf = 0; rf < 4; ++rf)
#pragma unroll
      for (int cf = 0; cf < 8; ++cf) acc[rf][cf] = (f32x4){0.f, 0.f, 0.f, 0.f};

#pragma unroll
    for (int ks = 0; ks < 16; ++ks) {
      short8 ag[4];
#pragma unroll
      for (int rf = 0; rf < 4; ++rf) {
        const float* ap = a0 + rf * (16 * DDIM) + ks * 32;
        const float4 f0 = *(const float4*)ap;
        const float4 f1 = *(const float4*)(ap + 4);
        short8 v;
        v[0] = (short)f2bf(f0.x); v[1] = (short)f2bf(f0.y);
        v[2] = (short)f2bf(f0.z); v[3] = (short)f2bf(f0.w);
        v[4] = (short)f2bf(f1.x); v[5] = (short)f2bf(f1.y);
        v[6] = (short)f2bf(f1.z); v[7] = (short)f2bf(f1.w);
        ag[rf] = v;
      }
      const unsigned kb = (bofs | ((unsigned)ks << 6)) ^ xm;
#pragma unroll
      for (int cf = 0; cf < 8; ++cf) {
        const short8 bfr = *(const short8*)(lbuf + kb + (unsigned)cf * 16384u);
        acc[0][cf] = __builtin_amdgcn_mfma_f32_16x16x32_bf16(ag[0], bfr, acc[0][cf], 0, 0, 0);
        acc[1][cf] = __builtin_amdgcn_mfma_f32_16x16x32_bf16(ag[1], bfr, acc[1][cf], 0, 0, 0);
        acc[2][cf] = __builtin_amdgcn_mfma_f32_16x16x32_bf16(ag[2], bfr, acc[2][cf], 0, 0, 0);
        acc[3][cf] = __builtin_amdgcn_mfma_f32_16x16x32_bf16(ag[3], bfr, acc[3][cf], 0, 0, 0);
      }
    }

    // partial LSE epilogue: C layout col = l15, row = lgrp*4 + reg
#pragma unroll
    for (int rf = 0; rf < 4; ++rf)
#pragma unroll
      for (int r = 0; r < 4; ++r) {
        const int row = rowB + rf * 16 + lgrp * 4 + r;
        const int tc = targets[row];
        float s = 0.f, tv = NEG_BIG;
#pragma unroll
        for (int cf = 0; cf < 8; ++cf) {
          const int col = p128 + cf * 16 + l15;
          const float z = fmaf(acc[rf][cf][r], L2E, bpad[col]);
          if (col == tc) tv = z;
          s += __builtin_amdgcn_exp2f(z);
        }
#pragma unroll
        for (int st = 1; st <= 8; st <<= 1) {
          s += __shfl_xor(s, st, 64);
          tv = fmaxf(tv, __shfl_xor(tv, st, 64));
        }
        if (l15 == 0) {
          spart[(size_t)p * BTOT + row]  = s;
          tvpart[(size_t)p * BTOT + row] = tv;
        }
      }
  }
}

// ---- combine 8 panel-partials -> loss, + hi-16 histogram ----
__global__ void combine_hist(const float* __restrict__ spart,
                             const float* __restrict__ tvpart,
                             float* __restrict__ losses,
                             unsigned* __restrict__ hHi) {
  const int row = blockIdx.x * 256 + threadIdx.x;
  float s = 0.f, tv = NEG_BIG;
#pragma unroll
  for (int p = 0; p < 8; ++p) {
    s  += spart[(size_t)p * BTOT + row];
    tv  = fmaxf(tv, tvpart[(size_t)p * BTOT + row]);
  }
  float loss = LN2 * (__builtin_amdgcn_logf(s) - tv);
  loss = fmaxf(loss, 0.f);
  losses[row] = loss;
  atomicAdd(&hHi[__float_as_uint(loss) >> 16], 1u);
}

// ---- level scan: find bin containing the k-th largest; 1 block x 256 threads ----
__global__ void scan_level(const unsigned* __restrict__ hist,
                           unsigned* __restrict__ state, const int level) {
  const int t = threadIdx.x;
  __shared__ unsigned sh[256];
  const unsigned k       = (level == 0) ? (unsigned)KSEL : state[1];
  const unsigned oldpref = (level == 0) ? 0u : state[0];

  unsigned gs = 0;
  const uint4* hp = (const uint4*)(hist + t * 256);
#pragma unroll 4
  for (int i = 0; i < 64; ++i) { const uint4 h = hp[i]; gs += h.x + h.y + h.z + h.w; }
  sh[t] = gs;
  __syncthreads();
  for (int off = 1; off < 256; off <<= 1) {   // inclusive suffix scan
    unsigned v = sh[t];
    if (t + off < 256) v += sh[t + off];
    __syncthreads();
    sh[t] = v;
    __syncthreads();
  }
  const unsigned incl  = sh[t];
  const unsigned above = (t < 255) ? sh[t + 1] : 0u;
  if (above < k && k <= incl) {          // exactly one thread
    unsigned kk = k - above;
    int bkt = 255;
    for (; bkt > 0; --bkt) {
      const unsigned c = hist[t * 256 + bkt];
      if (kk <= c) break;
      kk -= c;
    }
    const unsigned bin = (unsigned)(t * 256 + bkt);
    if (level == 0) { state[0] = bin << 16;      state[1] = kk; }
    else            { state[0] = oldpref | bin;  state[1] = kk; }
  }
}

__global__ void hist_lo(const float* __restrict__ losses,
                        const unsigned* __restrict__ state,
                        unsigned* __restrict__ hLo) {
  const unsigned pref = state[0] >> 16;
  const int i = blockIdx.x * 256 + threadIdx.x;
  const unsigned u = ((const unsigned*)losses)[i];
  if ((u >> 16) == pref) atomicAdd(&hLo[u & 0xFFFFu], 1u);
}

// ---- deterministic sum/count of values strictly greater than threshold ----
__global__ void ohem_sum(const float* __restrict__ losses,
                         const unsigned* __restrict__ state,
                         float* __restrict__ psum, unsigned* __restrict__ pcnt) {
  const unsigned ut = state[0];
  const int i = blockIdx.x * 256 + threadIdx.x;
  const float v = losses[i];
  const unsigned u = __float_as_uint(v);
  float    sv = (u > ut) ? v  : 0.f;
  unsigned sc = (u > ut) ? 1u : 0u;
#pragma unroll
  for (int st = 32; st >= 1; st >>= 1) {
    sv += __shfl_xor(sv, st, 64);
    sc += __shfl_xor(sc, st, 64);
  }
  __shared__ float    wsum[4];
  __shared__ unsigned wcnt[4];
  const int w = threadIdx.x >> 6;
  if ((threadIdx.x & 63) == 0) { wsum[w] = sv; wcnt[w] = sc; }
  __syncthreads();
  if (threadIdx.x == 0) {
    psum[blockIdx.x] = wsum[0] + wsum[1] + wsum[2] + wsum[3];
    pcnt[blockIdx.x] = wcnt[0] + wcnt[1] + wcnt[2] + wcnt[3];
  }
}

__global__ void ohem_final(const float* __restrict__ psum,
                           const unsigned* __restrict__ pcnt,
                           const unsigned* __restrict__ state,
                           float* __restrict__ out) {
  float    sv = psum[threadIdx.x];
  unsigned sc = pcnt[threadIdx.x];
#pragma unroll
  for (int st = 32; st >= 1; st >>= 1) {
    sv += __shfl_xor(sv, st, 64);
    sc += __shfl_xor(sc, st, 64);
  }
  __shared__ float    wsum[4];
  __shared__ unsigned wcnt[4];
  const int w = threadIdx.x >> 6;
  if ((threadIdx.x & 63) == 0) { wsum[w] = sv; wcnt[w] = sc; }
  __syncthreads();
  if (threadIdx.x == 0) {
    const float    sum = wsum[0] + wsum[1] + wsum[2] + wsum[3];
    const unsigned cnt = wcnt[0] + wcnt[1] + wcnt[2] + wcnt[3];
    const float t = __uint_as_float(state[0]);
    out[0] = (sum + (float)(KSEL - cnt) * t) / (float)KSEL;
  }
}

extern "C" void kernel_launch(void* const* d_in, const int* in_sizes, int n_in,
                              void* d_out, int out_size, void* d_ws, size_t ws_size,
                              hipStream_t stream) {
  const float* feat    = (const float*)d_in[0];
  const int*   targets = (const int*)d_in[1];
  const float* W       = (const float*)d_in[2];
  const float* b       = (const float*)d_in[3];
  float* out = (float*)d_out;

  char* ws = (char*)d_ws;
  unsigned short* Wg     = (unsigned short*)ws;              // 1 MiB (8 swizzled panels)
  float*          bp     = (float*)(ws + 1048576);           // 4 KiB
  float*          spart  = (float*)(ws + 1052672);           // 2 MiB
  float*          tvpart = (float*)(ws + 3149824);           // 2 MiB
  float*          losses = (float*)(ws + 5246976);           // 256 KiB
  unsigned*       hHi    = (unsigned*)(ws + 5509120);        // 256 KiB
  unsigned*       hLo    = (unsigned*)(ws + 5771264);        // 256 KiB (contiguous after hHi)
  unsigned*       state  = (unsigned*)(ws + 6033408);        // 256 B
  float*          psum   = (float*)(ws + 6033664);           // 1 KiB
  unsigned*       pcnt   = (unsigned*)(ws + 6034688);        // 1 KiB

  hipFuncSetAttribute((const void*)ohem_losses,
                      hipFuncAttributeMaxDynamicSharedMemorySize, 131072);

  prep_all<<<385, 256, 0, stream>>>(W, b, Wg, bp, hHi);      // hHi..hLo zeroed
  ohem_losses<<<256, 512, 131072, stream>>>(feat, targets, Wg, bp, spart, tvpart);
  combine_hist<<<256, 256, 0, stream>>>(spart, tvpart, losses, hHi);
  scan_level<<<1, 256, 0, stream>>>(hHi, state, 0);
  hist_lo<<<256, 256, 0, stream>>>(losses, state, hLo);
  scan_level<<<1, 256, 0, stream>>>(hLo, state, 1);
  ohem_sum<<<256, 256, 0, stream>>>(losses, state, psum, pcnt);
  ohem_final<<<1, 256, 0, stream>>>(psum, pcnt, state, out);
}